// Round 1
// baseline (61.849 us; speedup 1.0000x reference)
//
#include <hip/hip_runtime.h>

// Problem constants (fixed by the reference): D_IN=256, D_OUT=32.
constexpr int DIN  = 256;
constexpr int DOUT = 32;
constexpr int ET   = 128;   // entities per block
constexpr int KT   = 64;    // k-tile
constexpr int EPAD = KT + 4; // pad row to 68 floats: 16B-aligned rows, conflict-free strided reads

// Block: 256 threads = 32 entity-groups (eg) x 8 output-groups (og).
// Each thread computes a 4x4 tile: entities e = eg + i*32 (i=0..3),
// outputs o = og*4 + j (j=0..3).
__global__ __launch_bounds__(256)
void encoder_kernel(const float* __restrict__ emb,
                    const float* __restrict__ weight,
                    const float* __restrict__ bias,
                    const int*   __restrict__ ex,
                    const int*   __restrict__ ey,
                    const int*   __restrict__ enum_,
                    const int*   __restrict__ pW,
                    float*       __restrict__ out,
                    int N, int nent, int HW)
{
    __shared__ float s_emb[ET][EPAD];     // 128 x 68 x 4B = 34 KB
    __shared__ float s_w[KT * DOUT];      // 64 x 32 x 4B  =  8 KB

    const int tid = threadIdx.x;
    const int og  = tid & 7;
    const int eg  = tid >> 3;
    const int eb  = blockIdx.x * ET;

    float acc[4][4];
    #pragma unroll
    for (int i = 0; i < 4; ++i)
        #pragma unroll
        for (int j = 0; j < 4; ++j) acc[i][j] = 0.f;

    for (int kt = 0; kt < DIN; kt += KT) {
        // --- stage weight tile: rows kt..kt+KT-1, all 32 cols (contiguous 2048 floats)
        {
            const float4* src = reinterpret_cast<const float4*>(weight + (size_t)kt * DOUT);
            float4* dst = reinterpret_cast<float4*>(s_w);
            dst[tid]       = src[tid];
            dst[tid + 256] = src[tid + 256];
        }
        // --- stage emb tile: 128 rows x 64 floats = 2048 float4, 8 per thread
        #pragma unroll
        for (int r = 0; r < 8; ++r) {
            int f  = tid + r * 256;       // float4 index
            int e  = f >> 4;              // row (0..127)
            int kk = (f & 15) << 2;       // col (0..60 step 4)
            int eglob = eb + e;
            if (eglob >= nent) eglob = nent - 1;   // safety clamp
            float4 v = *reinterpret_cast<const float4*>(emb + (size_t)eglob * DIN + kt + kk);
            *reinterpret_cast<float4*>(&s_emb[e][kk]) = v;
        }
        __syncthreads();

        // --- compute: per thread 4 entities x 4 outputs, k in steps of 4
        #pragma unroll
        for (int k = 0; k < KT; k += 4) {
            float wv[16];   // wv[kk*4 + j] = w[kt+k+kk][og*4+j]
            #pragma unroll
            for (int kk = 0; kk < 4; ++kk)
                *reinterpret_cast<float4*>(&wv[kk * 4]) =
                    *reinterpret_cast<const float4*>(&s_w[(k + kk) * DOUT + og * 4]);
            #pragma unroll
            for (int i = 0; i < 4; ++i) {
                float ev[4];
                *reinterpret_cast<float4*>(ev) =
                    *reinterpret_cast<const float4*>(&s_emb[eg + i * 32][k]);
                #pragma unroll
                for (int j = 0; j < 4; ++j)
                    acc[i][j] += ev[0] * wv[0 * 4 + j] + ev[1] * wv[1 * 4 + j]
                               + ev[2] * wv[2 * 4 + j] + ev[3] * wv[3 * 4 + j];
            }
        }
        __syncthreads();
    }

    // --- epilogue: bias + relu + mask + scatter-add
    const int W = *pW;
    float bv[4];
    *reinterpret_cast<float4*>(bv) = *reinterpret_cast<const float4*>(bias + og * 4);

    #pragma unroll
    for (int i = 0; i < 4; ++i) {
        int ent = eb + eg + i * 32;
        if (ent >= nent) continue;
        int b = ent / N;
        int n = ent - b * N;
        if (n >= enum_[b]) continue;          // masked (padded) entity
        int x = ex[ent];
        int y = ey[ent];
        float* dst = out + ((size_t)b * DOUT + og * 4) * (size_t)HW + (size_t)y * W + x;
        #pragma unroll
        for (int j = 0; j < 4; ++j) {
            float v = acc[i][j] + bv[j];
            v = fmaxf(v, 0.f);
            if (v != 0.f) atomicAdd(dst + (size_t)j * HW, v);
        }
    }
}

extern "C" void kernel_launch(void* const* d_in, const int* in_sizes, int n_in,
                              void* d_out, int out_size, void* d_ws, size_t ws_size,
                              hipStream_t stream) {
    const float* emb    = (const float*)d_in[0];
    const float* weight = (const float*)d_in[1];
    const float* bias   = (const float*)d_in[2];
    const int*   ex     = (const int*)d_in[3];
    const int*   ey     = (const int*)d_in[4];
    const int*   en     = (const int*)d_in[5];
    const int*   pW     = (const int*)d_in[7];
    float*       out    = (float*)d_out;

    const int nent = in_sizes[3];          // B*N
    const int B    = in_sizes[5];
    const int N    = nent / B;
    const int HW   = (int)((size_t)out_size / ((size_t)B * DOUT));

    // Full zero of the output every call (scatter-add target; harness does not
    // re-poison between replays, so this is required for determinism).
    hipMemsetAsync(d_out, 0, (size_t)out_size * sizeof(float), stream);

    const int blocks = (nent + ET - 1) / ET;
    encoder_kernel<<<blocks, 256, 0, stream>>>(emb, weight, bias, ex, ey, en, pW,
                                               out, N, nent, HW);
}